// Round 16
// baseline (74.773 us; speedup 1.0000x reference)
//
#include <hip/hip_runtime.h>
#include <math.h>

#define HEADS 8
#define LVLS  4
#define PTS   8
#define NREF  4
#define DH    32
#define DD    256
#define NQc   5000
#define BATCH 2
#define NVc   13294
#define RVr   (BATCH * NVc)   // 26588
#define RQr   (BATCH * NQc)   // 10000

#define NJV 832               // value jobs: 416 row-tiles(64) x 2 col-tiles(128)
#define NJQ 942               // query jobs: 157 row-tiles(64) x 6 col-tiles(128)
#define NJOBS (NJV + NJQ)

#define NEV (RVr * 256)       // 6806528 value elems
#define NEQ (RQr * 256)       // 2560000 query elems
#define NCV ((NEV + 4095) / 4096)   // 1662 convert blocks (value)
#define NCQ ((NEQ + 4095) / 4096)   // 625  convert blocks (query)

using f16x8 = __attribute__((ext_vector_type(8))) _Float16;
using f16x4 = __attribute__((ext_vector_type(4))) _Float16;
using f32x4 = __attribute__((ext_vector_type(4))) float;
using h2    = __attribute__((ext_vector_type(2))) _Float16;

__device__ __forceinline__ int pack2(float w) {
    _Float16 h = (_Float16)w;
    h2 v = { h, h };
    return __builtin_bit_cast(int, v);
}

// ---------------------------------------------------------------------------
// Prep (one dispatch): [0,64) transpose weights to fp16 W^T[n][k];
// [64,...) stream-convert value & query f32 -> fp16 (same row-major layout).
// ---------------------------------------------------------------------------
__global__ __launch_bounds__(256) void prep_kernel(
    const float* __restrict__ value, const float* __restrict__ query,
    const float* __restrict__ Wv, const float* __restrict__ Wo,
    const float* __restrict__ Wa,
    _Float16* __restrict__ a16v, _Float16* __restrict__ a16q,
    _Float16* __restrict__ wtv, _Float16* __restrict__ wto,
    _Float16* __restrict__ wta)
{
    const int bid = blockIdx.x;
    const int t   = threadIdx.x;
    if (bid < 64) {
        __shared__ float tl[64][65];
        const float* src; _Float16* dst; int N, kt, nt;
        if (bid < 16)      { src = Wv; dst = wtv; N = 256; kt = bid & 3;        nt = bid >> 2; }
        else if (bid < 48) { src = Wo; dst = wto; N = 512; kt = (bid - 16) & 3; nt = (bid - 16) >> 2; }
        else               { src = Wa; dst = wta; N = 256; kt = (bid - 48) & 3; nt = (bid - 48) >> 2; }
        const int k0 = kt * 64, n0 = nt * 64;
        const int c  = t & 63, r4 = t >> 6;
        #pragma unroll
        for (int i = 0; i < 16; ++i) {
            const int r = r4 + i * 4;
            tl[r][c] = src[(size_t)(k0 + r) * N + n0 + c];
        }
        __syncthreads();
        #pragma unroll
        for (int i = 0; i < 16; ++i) {
            const int r = r4 + i * 4;   // n-local
            dst[(size_t)(n0 + r) * 256 + k0 + c] = (_Float16)tl[c][r];
        }
        return;
    }
    // stream conversion: 4096 elems per block
    const int cid = bid - 64;
    const float* src; _Float16* dst; int n; size_t base;
    if (cid < NCV) { src = value; dst = a16v; n = NEV; base = (size_t)cid * 4096; }
    else           { src = query; dst = a16q; n = NEQ; base = (size_t)(cid - NCV) * 4096; }
    #pragma unroll
    for (int i = 0; i < 4; ++i) {
        const size_t idx = base + i * 1024 + t * 4;
        if (idx < (size_t)n) {
            const float4 v = *(const float4*)&src[idx];
            f16x4 pk = { (_Float16)v.x, (_Float16)v.y, (_Float16)v.z, (_Float16)v.w };
            *(f16x4*)&dst[idx] = pk;
        }
    }
}

// ---------------------------------------------------------------------------
// Uber MFMA GEMM: both operands staged via global_load_lds (A pre-converted
// to fp16 by prep) -> zero VALU staging inside the K-loop.
//   job < NJV : v_f16 (HEAD-MAJOR: [b][head][NV][32] fp16) = value @ Wv + bv
//   else      : offa[RQ][768](fp16)  = query @ [Wo|Wa] + [bo|ba]
// Tile 64x128, BK=64, 4 waves (2x2), wave tile 32x64, acc 2x4. LDS 24KB.
// ---------------------------------------------------------------------------
__global__ __launch_bounds__(256) void gemm_uber_kernel(
    const _Float16* __restrict__ a16v, const _Float16* __restrict__ a16q,
    const _Float16* __restrict__ wtv, const _Float16* __restrict__ wtoa,
    const float* __restrict__ bv, const float* __restrict__ bo,
    const float* __restrict__ ba,
    _Float16* __restrict__ v_f16, _Float16* __restrict__ offa)
{
    __shared__ _Float16 aL[64][64];    // [row][k] linear, swizzled slots
    __shared__ _Float16 bL[128][64];   // [n][k]  linear, swizzled slots

    const int t    = threadIdx.x;
    const int lane = t & 63;
    const int wid  = t >> 6;
    const int wr   = wid >> 1;
    const int wc   = wid & 1;

    const int job = blockIdx.x;
    const bool isV = job < NJV;
    const _Float16* A; const _Float16* WT; int r0, ct;
    if (isV) { A = a16v; WT = wtv;  r0 = (job >> 1) * 64;  ct = job & 1; }
    else     { const int j2 = job - NJV;
               A = a16q; WT = wtoa; r0 = (j2 / 6) * 64;    ct = j2 % 6; }
    const int c0 = ct * 128;

    f32x4 acc[2][4] = {};

    const int brow  = lane >> 3;                 // 0..7 row-in-chunk
    const int bslot = (lane & 7) ^ brow;         // swizzled 16B source slot
    const int lm  = lane & 15;
    const int khi = lane >> 4;

    for (int kc = 0; kc < 256; kc += 64) {
        __syncthreads();
        // B tile: 128n x 64k = 16KB = 16 chunks of 1KB; wave owns 4.
        #pragma unroll
        for (int cch = 0; cch < 4; ++cch) {
            const int ch  = wid * 4 + cch;
            const int row = ch * 8 + brow;
            const _Float16* src = WT + (size_t)(c0 + row) * 256 + kc + bslot * 8;
            char* ldst = (char*)&bL[0][0] + ch * 1024;
            __builtin_amdgcn_global_load_lds(
                (const __attribute__((address_space(1))) void*)src,
                (__attribute__((address_space(3))) void*)ldst, 16, 0, 0);
        }
        // A tile: 64r x 64k = 8KB = 8 chunks of 1KB; wave owns 2.
        #pragma unroll
        for (int cch = 0; cch < 2; ++cch) {
            const int ch  = wid * 2 + cch;
            const int row = ch * 8 + brow;
            const _Float16* src = A + (size_t)(r0 + row) * 256 + kc + bslot * 8;
            char* ldst = (char*)&aL[0][0] + ch * 1024;
            __builtin_amdgcn_global_load_lds(
                (const __attribute__((address_space(1))) void*)src,
                (__attribute__((address_space(3))) void*)ldst, 16, 0, 0);
        }
        __syncthreads();

        const char* bB = (const char*)&bL[0][0];
        const char* aB = (const char*)&aL[0][0];
        #pragma unroll
        for (int kk = 0; kk < 2; ++kk) {
            const int slot = kk * 4 + khi;
            f16x8 bfrag[4];
            #pragma unroll
            for (int nf = 0; nf < 4; ++nf) {
                const int row = wc * 64 + nf * 16 + lm;
                bfrag[nf] = *(const f16x8*)(bB + row * 128 + ((slot ^ (row & 7)) << 4));
            }
            #pragma unroll
            for (int m = 0; m < 2; ++m) {
                const int arow = wr * 32 + m * 16 + lm;
                const f16x8 afrag = *(const f16x8*)(aB + arow * 128 + ((slot ^ (arow & 7)) << 4));
                #pragma unroll
                for (int nf = 0; nf < 4; ++nf)
                    acc[m][nf] = __builtin_amdgcn_mfma_f32_16x16x32_f16(
                        afrag, bfrag[nf], acc[m][nf], 0, 0, 0);
            }
        }
    }

    const int lq = lane >> 4;
    if (isV) {
        #pragma unroll
        for (int nf = 0; nf < 4; ++nf) {
            const int col = c0 + wc * 64 + nf * 16 + lm;   // h*32 + ch
            const int hh = col >> 5, ch = col & 31;
            const float bb = bv[col];
            #pragma unroll
            for (int m = 0; m < 2; ++m)
                #pragma unroll
                for (int r = 0; r < 4; ++r) {
                    const int row = r0 + wr * 32 + m * 16 + lq * 4 + r;
                    if (row < RVr) {
                        const int b   = (row >= NVc) ? 1 : 0;
                        const int pix = row - b * NVc;
                        v_f16[(((size_t)(b * HEADS + hh) * NVc) + pix) * 32 + ch] =
                            (_Float16)(acc[m][nf][r] + bb);
                    }
                }
        }
    } else {
        #pragma unroll
        for (int nf = 0; nf < 4; ++nf) {
            const int col = c0 + wc * 64 + nf * 16 + lm;
            const float bb = (col < 512) ? bo[col] : ba[col - 512];
            #pragma unroll
            for (int m = 0; m < 2; ++m)
                #pragma unroll
                for (int r = 0; r < 4; ++r) {
                    const int row = r0 + wr * 32 + m * 16 + lq * 4 + r;
                    if (row < RQr) offa[(size_t)row * 768 + col] = (_Float16)(acc[m][nf][r] + bb);
                }
        }
    }
}

// ---------------------------------------------------------------------------
// Sampling: block = 128 threads = one (bq-PAIR, h-half). MERGED X-CORNERS:
// v is head-major so the x0/x1 pixels of a sample row are ADJACENT 64B
// blocks -> ONE 8-lane x 16B contiguous 128B span per (point, y-corner)
// instead of two scattered 64B reads. Gather instructions and L1/TA
// requests HALVE (R13-R15 showed the kernel is request-rate-bound, not
// locality- or ILP-bound). Anchor = UNCLAMPED x0: invalid x handled by
// zero weights; +-64B overreads land in adjacent allocated ws regions.
// Descriptor per (point, ycorner): int4 {addr(x0 block), wA, wB, pad}.
// Lane map within 32-lane h-group: yc(1b)|po(1b)|xh(1b)|oct(2b).
// Reduction folds {xh, po, yc} = masks 4, 8, 16. XCD parity kept
// (half = blockIdx&1 -> fixed 4-slab 3.4MB L2 set per XCD).
// ---------------------------------------------------------------------------
__global__ __launch_bounds__(128) void sample_kernel(
    const _Float16* __restrict__ v,    // (B*HEADS*NV) x 32 fp16, head-major
    const _Float16* __restrict__ offa, // (B*NQ) x 768 fp16: [0:512) offsets, [512:768) logits
    const float* __restrict__ refp,    // (B, NQ, NREF, 2)
    float* __restrict__ out)           // (B, NQ, 256)
{
    __shared__ int4 swa[2][4][32][2];  // [sub][hl][j][ycorner]: {addr, wA, wB, pad}

    const int t    = threadIdx.x;
    const int hl   = t >> 5;           // h-group within block, 0..3
    const int j    = t & 31;
    const int pair = blockIdx.x >> 1;
    const int half = blockIdx.x & 1;
    const int h    = half * 4 + hl;
    const int bq0  = pair * 2;
    const int b    = bq0 / NQc;

    // ---- stage 1: both bq's per thread, 2 merged descriptors each ----
    {
        const int l = j >> 3;
        const int p = j & 7;
        const int r = p & 3;
        const int   Wi = (l == 0) ? 100 : (l == 1) ? 50 : (l == 2) ? 25 : 13;
        const float Wf = (float)Wi;
        const int   st = (l == 0) ? 0 : (l == 1) ? 10000 : (l == 2) ? 12500 : 13125;

        const _Float16* orow0 = offa + (size_t)bq0 * 768;
        const _Float16* orow1 = orow0 + 768;
        const float e0 = __expf((float)orow0[512 + h * 32 + j]);
        const float e1 = __expf((float)orow1[512 + h * 32 + j]);
        float s0 = e0, s1 = e1;
        #pragma unroll
        for (int mask = 16; mask >= 1; mask >>= 1) {   // 32-lane group = one h
            s0 += __shfl_xor(s0, mask, 64);
            s1 += __shfl_xor(s1, mask, 64);
        }
        const float aw0 = __fdividef(e0, s0);
        const float aw1 = __fdividef(e1, s1);

        const h2 oxy0 = *(const h2*)&orow0[h * 64 + j * 2];
        const h2 oxy1 = *(const h2*)&orow1[h * 64 + j * 2];
        const float2 rxy0 = *(const float2*)&refp[((size_t)bq0 * NREF + r) * 2];
        const float2 rxy1 = *(const float2*)&refp[((size_t)(bq0 + 1) * NREF + r) * 2];

        const int bb = ((b * HEADS + h) * NVc + st) * 64;   // byte base

        #pragma unroll
        for (int sub = 0; sub < 2; ++sub) {
            const float2 rxy = sub ? rxy1 : rxy0;
            const h2    oxy = sub ? oxy1 : oxy0;
            const float aw  = sub ? aw1  : aw0;

            const float x = rxy.x * Wf + (float)oxy[0] - 0.5f;
            const float y = rxy.y * Wf + (float)oxy[1] - 0.5f;
            const float x0f = floorf(x), y0f = floorf(y);
            const float dx = x - x0f, dy = y - y0f;
            const int x0 = (int)x0f, y0 = (int)y0f;
            const int x1 = x0 + 1,  y1 = y0 + 1;

            const bool vx0 = (x0 >= 0) && (x0 < Wi);
            const bool vx1 = (x1 >= 0) && (x1 < Wi);
            const bool vy0 = (y0 >= 0) && (y0 < Wi);
            const bool vy1 = (y1 >= 0) && (y1 < Wi);
            const int  yc0 = min(max(y0, 0), Wi - 1);
            const int  yc1 = min(max(y1, 0), Wi - 1);

            const float fy0 = (1.f - dy) * aw;
            const float fy1 = dy * aw;
            // anchor = UNCLAMPED x0: lane xh in {0,1} reads pixel x0+xh;
            // invalid sides carry weight 0 (overread stays in ws).
            const int rowb0 = bb + (yc0 * Wi + x0) * 64;
            const int rowb1 = bb + (yc1 * Wi + x0) * 64;

            swa[sub][hl][j][0] = make_int4(rowb0,
                pack2((vx0 && vy0) ? (1.f - dx) * fy0 : 0.f),
                pack2((vx1 && vy0) ? dx * fy0 : 0.f), 0);
            swa[sub][hl][j][1] = make_int4(rowb1,
                pack2((vx0 && vy1) ? (1.f - dx) * fy1 : 0.f),
                pack2((vx1 && vy1) ? dx * fy1 : 0.f), 0);
        }
    }

    // ---- stage 2: lane = (hl, yc, po, xh, oct); 16 iters, 1 load/stream ----
    const int yc   = (t >> 4) & 1;
    const int po   = (t >> 3) & 1;
    const int xh   = (t >> 2) & 1;
    const int boff = xh * 64 + (t & 3) * 16;   // byte offset within 128B span

    h2 a0 = {}, a1 = {}, a2 = {}, a3 = {};
    h2 c0 = {}, c1 = {}, c2 = {}, c3 = {};
    #pragma unroll 8
    for (int it = 0; it < 16; ++it) {
        const int pp = it * 2 + po;
        const int4 d0 = swa[0][hl][pp][yc];
        const int4 d1 = swa[1][hl][pp][yc];
        const h2 w0 = __builtin_bit_cast(h2, xh ? d0.z : d0.y);
        const h2 w1 = __builtin_bit_cast(h2, xh ? d1.z : d1.y);
        const f16x8 v0 = *(const f16x8*)((const char*)v + d0.x + boff);
        const f16x8 v1 = *(const f16x8*)((const char*)v + d1.x + boff);
        a0 += w0 * (h2){ v0[0], v0[1] };
        a1 += w0 * (h2){ v0[2], v0[3] };
        a2 += w0 * (h2){ v0[4], v0[5] };
        a3 += w0 * (h2){ v0[6], v0[7] };
        c0 += w1 * (h2){ v1[0], v1[1] };
        c1 += w1 * (h2){ v1[2], v1[3] };
        c2 += w1 * (h2){ v1[4], v1[5] };
        c3 += w1 * (h2){ v1[6], v1[7] };
    }

    // fold xh (mask 4), po (mask 8), yc (mask 16) — within wave
    #pragma unroll
    for (int mask = 4; mask <= 16; mask <<= 1) {
        a0 += __builtin_bit_cast(h2, __shfl_xor(__builtin_bit_cast(int, a0), mask, 64));
        a1 += __builtin_bit_cast(h2, __shfl_xor(__builtin_bit_cast(int, a1), mask, 64));
        a2 += __builtin_bit_cast(h2, __shfl_xor(__builtin_bit_cast(int, a2), mask, 64));
        a3 += __builtin_bit_cast(h2, __shfl_xor(__builtin_bit_cast(int, a3), mask, 64));
        c0 += __builtin_bit_cast(h2, __shfl_xor(__builtin_bit_cast(int, c0), mask, 64));
        c1 += __builtin_bit_cast(h2, __shfl_xor(__builtin_bit_cast(int, c1), mask, 64));
        c2 += __builtin_bit_cast(h2, __shfl_xor(__builtin_bit_cast(int, c2), mask, 64));
        c3 += __builtin_bit_cast(h2, __shfl_xor(__builtin_bit_cast(int, c3), mask, 64));
    }

    if ((t & 0x1c) == 0) {   // yc == po == xh == 0: 4 octet lanes per hl
        float* dst0 = &out[(size_t)bq0 * 256 + h * 32 + (t & 3) * 8];
        *(float4*)(dst0 + 0) = make_float4((float)a0[0], (float)a0[1],
                                           (float)a1[0], (float)a1[1]);
        *(float4*)(dst0 + 4) = make_float4((float)a2[0], (float)a2[1],
                                           (float)a3[0], (float)a3[1]);
        float* dst1 = dst0 + 256;
        *(float4*)(dst1 + 0) = make_float4((float)c0[0], (float)c0[1],
                                           (float)c1[0], (float)c1[1]);
        *(float4*)(dst1 + 4) = make_float4((float)c2[0], (float)c2[1],
                                           (float)c3[0], (float)c3[1]);
    }
}

extern "C" void kernel_launch(void* const* d_in, const int* in_sizes, int n_in,
                              void* d_out, int out_size, void* d_ws, size_t ws_size,
                              hipStream_t stream)
{
    const float* query  = (const float*)d_in[0];
    // d_in[1] = key (unused by the reference)
    const float* value  = (const float*)d_in[2];
    const float* refp   = (const float*)d_in[3];
    const float* Wv     = (const float*)d_in[6];
    const float* bv     = (const float*)d_in[7];
    const float* Wo     = (const float*)d_in[8];
    const float* bo     = (const float*)d_in[9];
    const float* Wa     = (const float*)d_in[10];
    const float* ba     = (const float*)d_in[11];
    float* out = (float*)d_out;

    // ws layout (fp16 elems). v_f16 sits BETWEEN a16q and offa so the
    // sample kernel's +-64B anchor overreads stay in allocated memory.
    _Float16* a16v  = (_Float16*)d_ws;                          // RV*256
    _Float16* a16q  = a16v + (size_t)RVr * 256;                 // RQ*256
    _Float16* v_f16 = a16q + (size_t)RQr * 256;                 // RV*256 (head-major)
    _Float16* offa  = v_f16 + (size_t)RVr * 256;                // RQ*768
    _Float16* wtv   = offa + (size_t)RQr * 768;                 // 256*256
    _Float16* wtoa  = wtv + 256 * 256;                          // 768*256

    prep_kernel<<<dim3(64 + NCV + NCQ), 256, 0, stream>>>(
        value, query, Wv, Wo, Wa, a16v, a16q, wtv, wtoa, wtoa + 512 * 256);

    gemm_uber_kernel<<<dim3(NJOBS), 256, 0, stream>>>(
        a16v, a16q, wtv, wtoa, bv, bo, ba, v_f16, offa);

    sample_kernel<<<dim3(RQr), 128, 0, stream>>>(
        v_f16, offa, refp, out);
}

// Round 17
// 70.305 us; speedup vs baseline: 1.0636x; 1.0636x over previous
//
#include <hip/hip_runtime.h>
#include <math.h>

#define HEADS 8
#define LVLS  4
#define PTS   8
#define NREF  4
#define DH    32
#define DD    256
#define NQc   5000
#define BATCH 2
#define NVc   13294
#define RVr   (BATCH * NVc)   // 26588
#define RQr   (BATCH * NQc)   // 10000

#define NJV 832               // value jobs: 416 row-tiles(64) x 2 col-tiles(128)
#define NJQ 942               // query jobs: 157 row-tiles(64) x 6 col-tiles(128)
#define NJOBS (NJV + NJQ)     // 1774 = 8*221 + 6

#define NEV (RVr * 256)       // 6806528 value elems
#define NEQ (RQr * 256)       // 2560000 query elems
#define NCV ((NEV + 4095) / 4096)   // 1662 convert blocks (value)
#define NCQ ((NEQ + 4095) / 4096)   // 625  convert blocks (query)

using f16x8 = __attribute__((ext_vector_type(8))) _Float16;
using f16x4 = __attribute__((ext_vector_type(4))) _Float16;
using f32x4 = __attribute__((ext_vector_type(4))) float;
using h2    = __attribute__((ext_vector_type(2))) _Float16;

__device__ __forceinline__ int pack2(float w) {
    _Float16 h = (_Float16)w;
    h2 v = { h, h };
    return __builtin_bit_cast(int, v);
}

// ---------------------------------------------------------------------------
// Prep (one dispatch): [0,64) transpose weights to fp16 W^T[n][k];
// [64,...) stream-convert value & query f32 -> fp16 (same row-major layout).
// ---------------------------------------------------------------------------
__global__ __launch_bounds__(256) void prep_kernel(
    const float* __restrict__ value, const float* __restrict__ query,
    const float* __restrict__ Wv, const float* __restrict__ Wo,
    const float* __restrict__ Wa,
    _Float16* __restrict__ a16v, _Float16* __restrict__ a16q,
    _Float16* __restrict__ wtv, _Float16* __restrict__ wto,
    _Float16* __restrict__ wta)
{
    const int bid = blockIdx.x;
    const int t   = threadIdx.x;
    if (bid < 64) {
        __shared__ float tl[64][65];
        const float* src; _Float16* dst; int N, kt, nt;
        if (bid < 16)      { src = Wv; dst = wtv; N = 256; kt = bid & 3;        nt = bid >> 2; }
        else if (bid < 48) { src = Wo; dst = wto; N = 512; kt = (bid - 16) & 3; nt = (bid - 16) >> 2; }
        else               { src = Wa; dst = wta; N = 256; kt = (bid - 48) & 3; nt = (bid - 48) >> 2; }
        const int k0 = kt * 64, n0 = nt * 64;
        const int c  = t & 63, r4 = t >> 6;
        #pragma unroll
        for (int i = 0; i < 16; ++i) {
            const int r = r4 + i * 4;
            tl[r][c] = src[(size_t)(k0 + r) * N + n0 + c];
        }
        __syncthreads();
        #pragma unroll
        for (int i = 0; i < 16; ++i) {
            const int r = r4 + i * 4;   // n-local
            dst[(size_t)(n0 + r) * 256 + k0 + c] = (_Float16)tl[c][r];
        }
        return;
    }
    // stream conversion: 4096 elems per block
    const int cid = bid - 64;
    const float* src; _Float16* dst; int n; size_t base;
    if (cid < NCV) { src = value; dst = a16v; n = NEV; base = (size_t)cid * 4096; }
    else           { src = query; dst = a16q; n = NEQ; base = (size_t)(cid - NCV) * 4096; }
    #pragma unroll
    for (int i = 0; i < 4; ++i) {
        const size_t idx = base + i * 1024 + t * 4;
        if (idx < (size_t)n) {
            const float4 v = *(const float4*)&src[idx];
            f16x4 pk = { (_Float16)v.x, (_Float16)v.y, (_Float16)v.z, (_Float16)v.w };
            *(f16x4*)&dst[idx] = pk;
        }
    }
}

// ---------------------------------------------------------------------------
// Uber MFMA GEMM with XCD-CHUNKED job swizzle: consecutive jobs share A
// row-tiles (value: 2 col-tile jobs, query: 6). Default round-robin puts
// them on DIFFERENT XCDs (private L2s) -> A re-read goes to HBM/L3.
// Bijective chunk map (m204): xcd = bid%8 serves a contiguous job range ->
// A-tile re-reads hit that XCD's L2.  1774 = 8*221+6: xcd<6 -> 222 jobs.
//   job < NJV : v_f16 (HEAD-MAJOR: [b][head][NV][32] fp16) = value @ Wv + bv
//   else      : offa[RQ][768](fp16)  = query @ [Wo|Wa] + [bo|ba]
// Tile 64x128, BK=64, 4 waves (2x2), wave tile 32x64, acc 2x4. LDS 24KB.
// Both operands staged via global_load_lds (A pre-converted to fp16).
// ---------------------------------------------------------------------------
__global__ __launch_bounds__(256) void gemm_uber_kernel(
    const _Float16* __restrict__ a16v, const _Float16* __restrict__ a16q,
    const _Float16* __restrict__ wtv, const _Float16* __restrict__ wtoa,
    const float* __restrict__ bv, const float* __restrict__ bo,
    const float* __restrict__ ba,
    _Float16* __restrict__ v_f16, _Float16* __restrict__ offa)
{
    __shared__ _Float16 aL[64][64];    // [row][k] linear, swizzled slots
    __shared__ _Float16 bL[128][64];   // [n][k]  linear, swizzled slots

    const int t    = threadIdx.x;
    const int lane = t & 63;
    const int wid  = t >> 6;
    const int wr   = wid >> 1;
    const int wc   = wid & 1;

    // bijective XCD-chunked swizzle: q=221, r=6
    const int bid  = blockIdx.x;
    const int xcd  = bid & 7;
    const int idx  = bid >> 3;
    const int job  = (xcd < 6) ? xcd * 222 + idx : 6 * 222 + (xcd - 6) * 221 + idx;

    const bool isV = job < NJV;
    const _Float16* A; const _Float16* WT; int r0, ct;
    if (isV) { A = a16v; WT = wtv;  r0 = (job >> 1) * 64;  ct = job & 1; }
    else     { const int j2 = job - NJV;
               A = a16q; WT = wtoa; r0 = (j2 / 6) * 64;    ct = j2 % 6; }
    const int c0 = ct * 128;

    f32x4 acc[2][4] = {};

    const int brow  = lane >> 3;                 // 0..7 row-in-chunk
    const int bslot = (lane & 7) ^ brow;         // swizzled 16B source slot
    const int lm  = lane & 15;
    const int khi = lane >> 4;

    for (int kc = 0; kc < 256; kc += 64) {
        __syncthreads();
        // B tile: 128n x 64k = 16KB = 16 chunks of 1KB; wave owns 4.
        #pragma unroll
        for (int cch = 0; cch < 4; ++cch) {
            const int ch  = wid * 4 + cch;
            const int row = ch * 8 + brow;
            const _Float16* src = WT + (size_t)(c0 + row) * 256 + kc + bslot * 8;
            char* ldst = (char*)&bL[0][0] + ch * 1024;
            __builtin_amdgcn_global_load_lds(
                (const __attribute__((address_space(1))) void*)src,
                (__attribute__((address_space(3))) void*)ldst, 16, 0, 0);
        }
        // A tile: 64r x 64k = 8KB = 8 chunks of 1KB; wave owns 2.
        #pragma unroll
        for (int cch = 0; cch < 2; ++cch) {
            const int ch  = wid * 2 + cch;
            const int row = ch * 8 + brow;
            const _Float16* src = A + (size_t)(r0 + row) * 256 + kc + bslot * 8;
            char* ldst = (char*)&aL[0][0] + ch * 1024;
            __builtin_amdgcn_global_load_lds(
                (const __attribute__((address_space(1))) void*)src,
                (__attribute__((address_space(3))) void*)ldst, 16, 0, 0);
        }
        __syncthreads();

        const char* bB = (const char*)&bL[0][0];
        const char* aB = (const char*)&aL[0][0];
        #pragma unroll
        for (int kk = 0; kk < 2; ++kk) {
            const int slot = kk * 4 + khi;
            f16x8 bfrag[4];
            #pragma unroll
            for (int nf = 0; nf < 4; ++nf) {
                const int row = wc * 64 + nf * 16 + lm;
                bfrag[nf] = *(const f16x8*)(bB + row * 128 + ((slot ^ (row & 7)) << 4));
            }
            #pragma unroll
            for (int m = 0; m < 2; ++m) {
                const int arow = wr * 32 + m * 16 + lm;
                const f16x8 afrag = *(const f16x8*)(aB + arow * 128 + ((slot ^ (arow & 7)) << 4));
                #pragma unroll
                for (int nf = 0; nf < 4; ++nf)
                    acc[m][nf] = __builtin_amdgcn_mfma_f32_16x16x32_f16(
                        afrag, bfrag[nf], acc[m][nf], 0, 0, 0);
            }
        }
    }

    const int lq = lane >> 4;
    if (isV) {
        #pragma unroll
        for (int nf = 0; nf < 4; ++nf) {
            const int col = c0 + wc * 64 + nf * 16 + lm;   // h*32 + ch
            const int hh = col >> 5, ch = col & 31;
            const float bb = bv[col];
            #pragma unroll
            for (int m = 0; m < 2; ++m)
                #pragma unroll
                for (int r = 0; r < 4; ++r) {
                    const int row = r0 + wr * 32 + m * 16 + lq * 4 + r;
                    if (row < RVr) {
                        const int b   = (row >= NVc) ? 1 : 0;
                        const int pix = row - b * NVc;
                        v_f16[(((size_t)(b * HEADS + hh) * NVc) + pix) * 32 + ch] =
                            (_Float16)(acc[m][nf][r] + bb);
                    }
                }
        }
    } else {
        #pragma unroll
        for (int nf = 0; nf < 4; ++nf) {
            const int col = c0 + wc * 64 + nf * 16 + lm;
            const float bb = (col < 512) ? bo[col] : ba[col - 512];
            #pragma unroll
            for (int m = 0; m < 2; ++m)
                #pragma unroll
                for (int r = 0; r < 4; ++r) {
                    const int row = r0 + wr * 32 + m * 16 + lq * 4 + r;
                    if (row < RQr) offa[(size_t)row * 768 + col] = (_Float16)(acc[m][nf][r] + bb);
                }
        }
    }
}

// ---------------------------------------------------------------------------
// Sampling (reverted to R14/R15 best structure — R16's merged-x-corner int4
// table caused 4.48M LDS bank conflicts and regressed): block = 128 threads
// = one (bq-PAIR, h-half); 2 independent gather streams per thread; XCD
// parity (half = blockIdx&1) keeps a fixed 4-slab (3.4MB) L2 working set.
// Stage 1: per-(h,j) thread computes softmax+location+4 corner descriptors
// for both bq's -> padded int2 table swa[sub][hl][j][0..4].
// Stage 2: thread = (hl, corner, po, octet); 16 iters x 2 gathers;
// 3-level {po,corner} shfl reduction; 2 stores.
// v HEAD-MAJOR [b][head][pixel][32ch]; x0/x1 corners adjacent 64B.
// ---------------------------------------------------------------------------
__global__ __launch_bounds__(128) void sample_kernel(
    const _Float16* __restrict__ v,    // (B*HEADS*NV) x 32 fp16, head-major
    const _Float16* __restrict__ offa, // (B*NQ) x 768 fp16: [0:512) offsets, [512:768) logits
    const float* __restrict__ refp,    // (B, NQ, NREF, 2)
    float* __restrict__ out)           // (B, NQ, 256)
{
    __shared__ int2 swa[2][4][32][5];  // [sub][hl][j][corner], padded row

    const int t    = threadIdx.x;
    const int hl   = t >> 5;           // h-group within block, 0..3
    const int j    = t & 31;
    const int pair = blockIdx.x >> 1;
    const int half = blockIdx.x & 1;
    const int h    = half * 4 + hl;
    const int bq0  = pair * 2;
    const int b    = bq0 / NQc;

    // ---- stage 1: both bq's per thread ----
    {
        const int l = j >> 3;
        const int p = j & 7;
        const int r = p & 3;
        const int   Wi = (l == 0) ? 100 : (l == 1) ? 50 : (l == 2) ? 25 : 13;
        const float Wf = (float)Wi;
        const int   st = (l == 0) ? 0 : (l == 1) ? 10000 : (l == 2) ? 12500 : 13125;

        const _Float16* orow0 = offa + (size_t)bq0 * 768;
        const _Float16* orow1 = orow0 + 768;
        const float e0 = __expf((float)orow0[512 + h * 32 + j]);
        const float e1 = __expf((float)orow1[512 + h * 32 + j]);
        float s0 = e0, s1 = e1;
        #pragma unroll
        for (int mask = 16; mask >= 1; mask >>= 1) {   // 32-lane group = one h
            s0 += __shfl_xor(s0, mask, 64);
            s1 += __shfl_xor(s1, mask, 64);
        }
        const float aw0 = __fdividef(e0, s0);
        const float aw1 = __fdividef(e1, s1);

        const h2 oxy0 = *(const h2*)&orow0[h * 64 + j * 2];
        const h2 oxy1 = *(const h2*)&orow1[h * 64 + j * 2];
        const float2 rxy0 = *(const float2*)&refp[((size_t)bq0 * NREF + r) * 2];
        const float2 rxy1 = *(const float2*)&refp[((size_t)(bq0 + 1) * NREF + r) * 2];

        const int bb = ((b * HEADS + h) * NVc + st) * 64;   // byte base

        #pragma unroll
        for (int sub = 0; sub < 2; ++sub) {
            const float2 rxy = sub ? rxy1 : rxy0;
            const h2    oxy = sub ? oxy1 : oxy0;
            const float aw  = sub ? aw1  : aw0;

            const float x = rxy.x * Wf + (float)oxy[0] - 0.5f;
            const float y = rxy.y * Wf + (float)oxy[1] - 0.5f;
            const float x0f = floorf(x), y0f = floorf(y);
            const float dx = x - x0f, dy = y - y0f;
            const int x0 = (int)x0f, y0 = (int)y0f;
            const int x1 = x0 + 1,  y1 = y0 + 1;

            const bool vx0 = (x0 >= 0) && (x0 < Wi);
            const bool vx1 = (x1 >= 0) && (x1 < Wi);
            const bool vy0 = (y0 >= 0) && (y0 < Wi);
            const bool vy1 = (y1 >= 0) && (y1 < Wi);
            const int  xc0 = min(max(x0, 0), Wi - 1);
            const int  xc1 = min(max(x1, 0), Wi - 1);
            const int  yc0 = min(max(y0, 0), Wi - 1);
            const int  yc1 = min(max(y1, 0), Wi - 1);

            const float fy0 = (1.f - dy) * aw;
            const float fy1 = dy * aw;
            const int rowb0 = bb + yc0 * Wi * 64;
            const int rowb1 = bb + yc1 * Wi * 64;

            swa[sub][hl][j][0] = make_int2(rowb0 + (xc0 << 6),
                pack2((vx0 && vy0) ? (1.f - dx) * fy0 : 0.f));
            swa[sub][hl][j][1] = make_int2(rowb0 + (xc1 << 6),
                pack2((vx1 && vy0) ? dx * fy0 : 0.f));
            swa[sub][hl][j][2] = make_int2(rowb1 + (xc0 << 6),
                pack2((vx0 && vy1) ? (1.f - dx) * fy1 : 0.f));
            swa[sub][hl][j][3] = make_int2(rowb1 + (xc1 << 6),
                pack2((vx1 && vy1) ? dx * fy1 : 0.f));
        }
    }

    // ---- stage 2: thread = (hl, corner, po, octet), both bq's ----
    const int corner = (t >> 3) & 3;
    const int po     = (t >> 2) & 1;
    const int cqb    = (t & 3) * 16;   // channel-octet byte offset within 64B

    h2 a0 = {}, a1 = {}, a2 = {}, a3 = {};
    h2 c0 = {}, c1 = {}, c2 = {}, c3 = {};
    #pragma unroll 8
    for (int it = 0; it < 16; ++it) {
        const int pp = it * 2 + po;
        const int2 d0 = swa[0][hl][pp][corner];
        const int2 d1 = swa[1][hl][pp][corner];
        const h2 w0 = __builtin_bit_cast(h2, d0.y);
        const h2 w1 = __builtin_bit_cast(h2, d1.y);
        const f16x8 v0 = *(const f16x8*)((const char*)v + d0.x + cqb);
        const f16x8 v1 = *(const f16x8*)((const char*)v + d1.x + cqb);
        a0 += w0 * (h2){ v0[0], v0[1] };
        a1 += w0 * (h2){ v0[2], v0[3] };
        a2 += w0 * (h2){ v0[4], v0[5] };
        a3 += w0 * (h2){ v0[6], v0[7] };
        c0 += w1 * (h2){ v1[0], v1[1] };
        c1 += w1 * (h2){ v1[2], v1[3] };
        c2 += w1 * (h2){ v1[4], v1[5] };
        c3 += w1 * (h2){ v1[6], v1[7] };
    }

    // fold po (mask 4) then corner (masks 8, 16) — 3 levels, within wave
    #pragma unroll
    for (int mask = 4; mask <= 16; mask <<= 1) {
        a0 += __builtin_bit_cast(h2, __shfl_xor(__builtin_bit_cast(int, a0), mask, 64));
        a1 += __builtin_bit_cast(h2, __shfl_xor(__builtin_bit_cast(int, a1), mask, 64));
        a2 += __builtin_bit_cast(h2, __shfl_xor(__builtin_bit_cast(int, a2), mask, 64));
        a3 += __builtin_bit_cast(h2, __shfl_xor(__builtin_bit_cast(int, a3), mask, 64));
        c0 += __builtin_bit_cast(h2, __shfl_xor(__builtin_bit_cast(int, c0), mask, 64));
        c1 += __builtin_bit_cast(h2, __shfl_xor(__builtin_bit_cast(int, c1), mask, 64));
        c2 += __builtin_bit_cast(h2, __shfl_xor(__builtin_bit_cast(int, c2), mask, 64));
        c3 += __builtin_bit_cast(h2, __shfl_xor(__builtin_bit_cast(int, c3), mask, 64));
    }

    if ((t & 0x1c) == 0) {   // po == 0 && corner == 0: 4 octet lanes per hl
        float* dst0 = &out[(size_t)bq0 * 256 + h * 32 + (t & 3) * 8];
        *(float4*)(dst0 + 0) = make_float4((float)a0[0], (float)a0[1],
                                           (float)a1[0], (float)a1[1]);
        *(float4*)(dst0 + 4) = make_float4((float)a2[0], (float)a2[1],
                                           (float)a3[0], (float)a3[1]);
        float* dst1 = dst0 + 256;
        *(float4*)(dst1 + 0) = make_float4((float)c0[0], (float)c0[1],
                                           (float)c1[0], (float)c1[1]);
        *(float4*)(dst1 + 4) = make_float4((float)c2[0], (float)c2[1],
                                           (float)c3[0], (float)c3[1]);
    }
}

extern "C" void kernel_launch(void* const* d_in, const int* in_sizes, int n_in,
                              void* d_out, int out_size, void* d_ws, size_t ws_size,
                              hipStream_t stream)
{
    const float* query  = (const float*)d_in[0];
    // d_in[1] = key (unused by the reference)
    const float* value  = (const float*)d_in[2];
    const float* refp   = (const float*)d_in[3];
    const float* Wv     = (const float*)d_in[6];
    const float* bv     = (const float*)d_in[7];
    const float* Wo     = (const float*)d_in[8];
    const float* bo     = (const float*)d_in[9];
    const float* Wa     = (const float*)d_in[10];
    const float* ba     = (const float*)d_in[11];
    float* out = (float*)d_out;

    // ws layout (fp16 elems). a16q must not be last: GEMM A-tail reads
    // spill a few rows past each region into the next (allocated) one.
    _Float16* a16v  = (_Float16*)d_ws;                          // RV*256
    _Float16* a16q  = a16v + (size_t)RVr * 256;                 // RQ*256
    _Float16* v_f16 = a16q + (size_t)RQr * 256;                 // RV*256 (head-major)
    _Float16* offa  = v_f16 + (size_t)RVr * 256;                // RQ*768
    _Float16* wtv   = offa + (size_t)RQr * 768;                 // 256*256
    _Float16* wtoa  = wtv + 256 * 256;                          // 768*256

    prep_kernel<<<dim3(64 + NCV + NCQ), 256, 0, stream>>>(
        value, query, Wv, Wo, Wa, a16v, a16q, wtv, wtoa, wtoa + 512 * 256);

    gemm_uber_kernel<<<dim3(NJOBS), 256, 0, stream>>>(
        a16v, a16q, wtv, wtoa, bv, bo, ba, v_f16, offa);

    sample_kernel<<<dim3(RQr), 128, 0, stream>>>(
        v_f16, offa, refp, out);
}